// Round 8
// baseline (306.121 us; speedup 1.0000x reference)
//
#include <hip/hip_runtime.h>
#include <math.h>
#include <stdint.h>

#define D_MODEL 1024
#define N_HEADS 16
#define HEAD_DIM 64
#define BATCH 2
#define SEQ 2048
#define TOKENS (BATCH * SEQ)   // 4096

typedef __attribute__((ext_vector_type(8))) short short8;      // 8 bf16
typedef __attribute__((ext_vector_type(8))) _Float16 half8;    // 8 fp16
typedef __attribute__((ext_vector_type(4))) float floatx4;     // MFMA C/D frag

#define BMFMA(a, b, c) __builtin_amdgcn_mfma_f32_16x16x32_bf16(a, b, c, 0, 0, 0)
#define HMFMA(a, b, c) __builtin_amdgcn_mfma_f32_16x16x32_f16(a, b, c, 0, 0, 0)

__device__ __forceinline__ unsigned short f2bf(float f) {
    uint32_t u = __float_as_uint(f);
    u += 0x7fffu + ((u >> 16) & 1u);
    return (unsigned short)(u >> 16);
}
__device__ __forceinline__ float bf2f(unsigned short h) {
    return __uint_as_float(((uint32_t)h) << 16);
}
__device__ __forceinline__ unsigned short f2h(float f) {
    union { _Float16 h; unsigned short u; } cv;
    cv.h = (_Float16)f;            // RNE
    return cv.u;
}
__device__ __forceinline__ float h2f(unsigned short u) {
    union { unsigned short u; _Float16 h; } cv;
    cv.u = u;
    return (float)cv.h;
}

// async global -> LDS, 16B per lane; LDS dest = wave-uniform base + lane*16
#define GLD_LDS16(gp, lp) __builtin_amdgcn_global_load_lds(                 \
    (const __attribute__((address_space(1))) void*)(gp),                    \
    (__attribute__((address_space(3))) void*)(lp), 16, 0, 0)

// ---------------------------------------------------------------------------
// Merged input prep:
//   blocks [0,2048)      : x -> Axh (single fp16 [4096][1024])
//   blocks [2048,5120)   : W_qkv -> Bt (transpose, single fp16 [3072n][1024k])
//   blocks [5120,6144)   : W_out -> Bt2 (transpose, single fp16 [1024n][1024k])
//   block  6144          : attention_mask -> bitmask; zero split-K flags
//   blocks [6145,6161)   : RoPE cos/sin table [t][32] float2
// ---------------------------------------------------------------------------
__global__ __launch_bounds__(256) void split_inputs(
    const float* __restrict__ X, const float* __restrict__ Wqkv,
    const float* __restrict__ Wout, const int* __restrict__ am,
    unsigned short* __restrict__ Axh, unsigned short* __restrict__ Bt,
    unsigned short* __restrict__ Bt2, unsigned long long* __restrict__ mbits,
    float2* __restrict__ tab, int* __restrict__ flags)
{
    __shared__ float t[32][33];
    const int tid = threadIdx.x;
    const int bid = blockIdx.x;
    if (bid < 2048) {
        const int idx = bid * 2048 + tid * 8;
        const int row = idx >> 10;
        const int c = idx & 1023;
        float4 v0 = *(const float4*)(X + (size_t)row * 1024 + c);
        float4 v1 = *(const float4*)(X + (size_t)row * 1024 + c + 4);
        float f[8] = {v0.x, v0.y, v0.z, v0.w, v1.x, v1.y, v1.z, v1.w};
        uint32_t p[4];
#pragma unroll
        for (int j = 0; j < 4; ++j)
            p[j] = (uint32_t)f2h(f[2 * j]) | ((uint32_t)f2h(f[2 * j + 1]) << 16);
        *(uint4*)(Axh + (size_t)row * 1024 + c) = *(uint4*)p;
    } else if (bid < 5120) {
        const int id = bid - 2048;                 // 0..3071
        const int n0 = (id % 96) * 32, k0 = (id / 96) * 32;
        const int c = tid & 31, r = tid >> 5;
#pragma unroll
        for (int i = 0; i < 4; ++i)
            t[r + 8 * i][c] = Wqkv[(size_t)(k0 + r + 8 * i) * 3072 + n0 + c];
        __syncthreads();
#pragma unroll
        for (int i = 0; i < 4; ++i) {
            int dn = r + 8 * i;
            Bt[(size_t)(n0 + dn) * 1024 + k0 + c] = f2h(t[c][dn]);
        }
    } else if (bid < 6144) {
        const int id = bid - 5120;                 // 0..1023: W_out 32x32 tiles
        const int n0 = (id & 31) * 32, k0 = (id >> 5) * 32;
        const int c = tid & 31, r = tid >> 5;
#pragma unroll
        for (int i = 0; i < 4; ++i)
            t[r + 8 * i][c] = Wout[(size_t)(k0 + r + 8 * i) * 1024 + n0 + c];
        __syncthreads();
#pragma unroll
        for (int i = 0; i < 4; ++i) {
            int dn = r + 8 * i;
            Bt2[(size_t)(n0 + dn) * 1024 + k0 + c] = f2h(t[c][dn]);
        }
    } else if (bid == 6144) {
        // mask bitmap: one uint64 per 64-token tile (B*SEQ/64 = 64 tiles)
        if (tid < 64) {
            const int* a = am + tid * 64;
            unsigned long long m = 0ull;
            for (int j = 0; j < 64; ++j)
                m |= (unsigned long long)(a[j] != 0 ? 1u : 0u) << j;
            mbits[tid] = m;
        }
        flags[tid] = 0;                            // 512 split-K merge flags
        flags[tid + 256] = 0;
    } else {
        // RoPE table: 2048 x 32 float2 (cos, sin)
        const int i = bid - 6145;                  // 0..15
#pragma unroll
        for (int e = 0; e < 16; ++e) {
            int idx = i * 4096 + e * 256 + tid;
            int tt = idx >> 5, pr = idx & 31;
            double ex = (double)(2 * pr) / 64.0;
            float inv = (float)exp2(-ex * 13.287712379549449);
            float ang = (float)tt * inv;
            float s, c;
            __sincosf(ang, &s, &c);
            tab[idx] = make_float2(c, s);
        }
    }
}

// ---------------------------------------------------------------------------
// FUSED QKV projection + RoPE + Q-scale + layout split (R17 epilogue) with
// R18 XCD-slab grid mapping: 768 blocks = 8 slabs (blockIdx%8 -> XCD) of
// 8 M-tiles x 12 N-tiles. Per-XCD working set: A 2MB + B 3MB ~= L2-resident
// (was: round-robin -> ~14.7MB/XCD -> 3.7x over-fetch + exposed latency).
// ---------------------------------------------------------------------------
__global__ __launch_bounds__(256) void gemm_qkv_fused(
    const unsigned short* __restrict__ Axh, const unsigned short* __restrict__ Bt,
    const float* __restrict__ bias, const float2* __restrict__ tab,
    unsigned short* __restrict__ Qh, unsigned short* __restrict__ Kh,
    unsigned short* __restrict__ Vh)
{
    __shared__ __align__(16) unsigned short sA0[4096], sA1[4096];
    __shared__ __align__(16) unsigned short sB0[4096], sB1[4096];

    const int tid = threadIdx.x;
    const int w = tid >> 6, lane = tid & 63;
    const int l15 = lane & 15, quad = lane >> 4;
    const int wm = w >> 1, wn = w & 1;

    const int lin = blockIdx.x;
    const int s = lin & 7;                 // XCD (HW round-robin on bid%8)
    const int loc = lin >> 3;              // 0..95 within slab
    const int m0 = ((s >> 1) * 8 + loc / 12) * 128;   // 4 slabs along M
    const int n0 = ((s & 1) * 12 + loc % 12) * 128;   // 2 slabs along N

    const int ch = (lane & 3) ^ ((lane >> 3) & 3);
    const int sw = (quad ^ ((l15 >> 1) & 3)) * 8;

    const unsigned short* aG[2];
    const unsigned short* bG[2];
#pragma unroll
    for (int i = 0; i < 2; ++i) {
        aG[i] = Axh + (size_t)(m0 + (w * 2 + i) * 16 + (lane >> 2)) * 1024 + ch * 8;
        bG[i] = Bt + (size_t)(n0 + (w * 2 + i) * 16 + (lane >> 2)) * 1024 + ch * 8;
    }

    floatx4 acc[4][4];
#pragma unroll
    for (int fm = 0; fm < 4; ++fm)
#pragma unroll
        for (int fn = 0; fn < 4; ++fn) acc[fm][fn] = (floatx4)0.f;

    for (int ks = 0; ks < 16; ++ks) {
        const int ko = ks * 64;
        __syncthreads();
#pragma unroll
        for (int i = 0; i < 2; ++i) {
            GLD_LDS16(aG[i] + ko,      sA0 + (w * 2 + i) * 512);
            GLD_LDS16(aG[i] + ko + 32, sA1 + (w * 2 + i) * 512);
            GLD_LDS16(bG[i] + ko,      sB0 + (w * 2 + i) * 512);
            GLD_LDS16(bG[i] + ko + 32, sB1 + (w * 2 + i) * 512);
        }
        __syncthreads();

        half8 a0[4], a1[4], b0[4], b1[4];
#pragma unroll
        for (int fm = 0; fm < 4; ++fm) {
            const int off = ((wm * 4 + fm) * 16 + l15) * 32 + sw;
            a0[fm] = *(const half8*)&sA0[off];
            a1[fm] = *(const half8*)&sA1[off];
        }
#pragma unroll
        for (int fn = 0; fn < 4; ++fn) {
            const int off = ((wn * 4 + fn) * 16 + l15) * 32 + sw;
            b0[fn] = *(const half8*)&sB0[off];
            b1[fn] = *(const half8*)&sB1[off];
        }
#pragma unroll
        for (int fm = 0; fm < 4; ++fm)
#pragma unroll
            for (int fn = 0; fn < 4; ++fn) {
                floatx4 a = acc[fm][fn];
                a = HMFMA(a0[fm], b0[fn], a);
                a = HMFMA(a1[fm], b1[fn], a);
                acc[fm][fn] = a;
            }
    }

    // ---- fused epilogue ----
    if (n0 < 2048) {
        // Q or K: bias + RoPE (partner in lane^1) + (Q: 1/8 scale)
        const bool isQ = (n0 < 1024);
        unsigned short* dst = isQ ? Qh : Kh;
        const float qs = isQ ? 0.125f : 1.0f;
#pragma unroll
        for (int fm = 0; fm < 4; ++fm)
#pragma unroll
            for (int fn = 0; fn < 4; ++fn) {
                const int col = n0 + (wn * 4 + fn) * 16 + l15;
                const int hcol = col & 1023;
                const int hh = hcol >> 6, d = hcol & 63;
                const int pr = d >> 1;
                const bool odd = (d & 1) != 0;
                const float bv = bias[col];
#pragma unroll
                for (int r = 0; r < 4; ++r) {
                    const int row = m0 + (wm * 4 + fm) * 16 + quad * 4 + r;
                    const int tg = row & 2047, bb = row >> 11;
                    float val = acc[fm][fn][r] + bv;
                    float part = __shfl_xor(val, 1);
                    const float2 cs = tab[tg * 32 + pr];
                    float res = odd ? (part * cs.y + val * cs.x)
                                    : (val * cs.x - part * cs.y);
                    dst[((size_t)(bb * 16 + hh) * SEQ + tg) * 64 + d] =
                        f2h(res * qs);
                }
            }
    } else {
        // V: bias, bf16, transposed [bh][d][2048]; 4 consecutive t per store
#pragma unroll
        for (int fm = 0; fm < 4; ++fm)
#pragma unroll
            for (int fn = 0; fn < 4; ++fn) {
                const int col = n0 + (wn * 4 + fn) * 16 + l15;
                const int hcol = col & 1023;
                const int hh = hcol >> 6, d = hcol & 63;
                const float bv = bias[col];
                const int row0 = m0 + (wm * 4 + fm) * 16 + quad * 4;
                const int tg0 = row0 & 2047, bb = row0 >> 11;
                uint32_t pk0 = (uint32_t)f2bf(acc[fm][fn][0] + bv)
                             | ((uint32_t)f2bf(acc[fm][fn][1] + bv) << 16);
                uint32_t pk1 = (uint32_t)f2bf(acc[fm][fn][2] + bv)
                             | ((uint32_t)f2bf(acc[fm][fn][3] + bv) << 16);
                *(uint2*)(Vh + ((size_t)(bb * 16 + hh) * 64 + d) * SEQ + tg0) =
                    make_uint2(pk0, pk1);
            }
    }
}

// ---------------------------------------------------------------------------
// Single-precision fp16 MFMA GEMM (out-projection), fp32 output.
// R18: XCD-slab mapping — grid = 8 slabs x (mPerSlab x nTilesN) blocks;
// slab working set A mPerSlab*256KB + B nTilesN*256KB kept <= 4MB L2.
// ---------------------------------------------------------------------------
template<int WM, int WN, int FM, int FN>
__global__ __launch_bounds__(256) void gemm_mfma_h(
    const unsigned short* __restrict__ A, int lda,
    const unsigned short* __restrict__ Bt, int ldb,
    const float* __restrict__ bias, float* __restrict__ C, int ldc,
    int mPerSlab, int nTilesN)
{
    constexpr int BM = WM * FM * 16;
    constexpr int BN = WN * FN * 16;
    constexpr int NA = BM / 64;
    constexpr int NB = BN / 64;

    __shared__ __align__(16) unsigned short sA0[BM * 32];
    __shared__ __align__(16) unsigned short sA1[BM * 32];
    __shared__ __align__(16) unsigned short sB0[BN * 32];
    __shared__ __align__(16) unsigned short sB1[BN * 32];

    const int tid = threadIdx.x;
    const int w = tid >> 6, lane = tid & 63;
    const int l15 = lane & 15, quad = lane >> 4;
    const int wm = w / WN, wn = w % WN;

    const int lin = blockIdx.x;
    const int s = lin & 7, loc = lin >> 3;
    const int m0 = (s * mPerSlab + loc / nTilesN) * BM;
    const int n0 = (loc % nTilesN) * BN;

    const int ch = (lane & 3) ^ ((lane >> 3) & 3);
    const int sw = (quad ^ ((l15 >> 1) & 3)) * 8;

    const unsigned short* aG[NA];
    const unsigned short* bG[NB];
#pragma unroll
    for (int i = 0; i < NA; ++i)
        aG[i] = A + (size_t)(m0 + (w * NA + i) * 16 + (lane >> 2)) * lda + ch * 8;
#pragma unroll
    for (int i = 0; i < NB; ++i)
        bG[i] = Bt + (size_t)(n0 + (w * NB + i) * 16 + (lane >> 2)) * ldb + ch * 8;

    floatx4 acc[FM][FN];
#pragma unroll
    for (int fm = 0; fm < FM; ++fm)
#pragma unroll
        for (int fn = 0; fn < FN; ++fn) acc[fm][fn] = (floatx4)0.f;

    for (int ks = 0; ks < 16; ++ks) {
        const int ko = ks * 64;
        __syncthreads();
#pragma unroll
        for (int i = 0; i < NA; ++i) {
            GLD_LDS16(aG[i] + ko,      sA0 + (w * NA + i) * 512);
            GLD_LDS16(aG[i] + ko + 32, sA1 + (w * NA + i) * 512);
        }
#pragma unroll
        for (int i = 0; i < NB; ++i) {
            GLD_LDS16(bG[i] + ko,      sB0 + (w * NB + i) * 512);
            GLD_LDS16(bG[i] + ko + 32, sB1 + (w * NB + i) * 512);
        }
        __syncthreads();

        half8 a0[FM], a1[FM], b0[FN], b1[FN];
#pragma unroll
        for (int fm = 0; fm < FM; ++fm) {
            const int off = ((wm * FM + fm) * 16 + l15) * 32 + sw;
            a0[fm] = *(const half8*)&sA0[off];
            a1[fm] = *(const half8*)&sA1[off];
        }
#pragma unroll
        for (int fn = 0; fn < FN; ++fn) {
            const int off = ((wn * FN + fn) * 16 + l15) * 32 + sw;
            b0[fn] = *(const half8*)&sB0[off];
            b1[fn] = *(const half8*)&sB1[off];
        }
#pragma unroll
        for (int fm = 0; fm < FM; ++fm)
#pragma unroll
            for (int fn = 0; fn < FN; ++fn) {
                floatx4 a = acc[fm][fn];
                a = HMFMA(a0[fm], b0[fn], a);
                a = HMFMA(a1[fm], b1[fn], a);
                acc[fm][fn] = a;
            }
    }

#pragma unroll
    for (int fm = 0; fm < FM; ++fm)
#pragma unroll
        for (int fn = 0; fn < FN; ++fn) {
            int col = n0 + (wn * FN + fn) * 16 + l15;
            float bv = bias[col];
#pragma unroll
            for (int r = 0; r < 4; ++r) {
                int row = m0 + (wm * FM + fm) * 16 + quad * 4 + r;
                C[(size_t)row * ldc + col] = acc[fm][fn][r] + bv;
            }
        }
}

// ---------------------------------------------------------------------------
// MFMA flash attention, R18: split-K (R16) with INLINE merge — the second
// chunk to finish a (bh,qt) pair merges partials itself (device-fence +
// atomic flag), deleting the flash_merge dispatch. Partial data is L2-hot.
// ---------------------------------------------------------------------------
__global__ __launch_bounds__(256, 6) void flash_mfma(
    const unsigned short* __restrict__ Qh, const unsigned short* __restrict__ Kh,
    const unsigned short* __restrict__ Vh,
    const unsigned long long* __restrict__ mbits,
    unsigned short* __restrict__ attnx,
    float* __restrict__ Opart, float* __restrict__ lpart,
    int* __restrict__ flags)
{
    __shared__ __align__(16) unsigned short sK[4096];
    __shared__ __align__(16) unsigned short sV[4096];
    __shared__ __align__(16) unsigned short sP[4096];
    __shared__ int sOld;

    const int tid = threadIdx.x;
    const int lane = tid & 63, w = tid >> 6;
    const int l15 = lane & 15, quad = lane >> 4;
    const int lin0 = blockIdx.x;
    const int xcd = lin0 & 7, idx = lin0 >> 3;     // 1536 = 8 XCD * 192
    const int bh = xcd * 4 + (idx & 3);            // 4 bh per XCD (L2-resident)
    const int rank = idx >> 2;                     // 0..47, heavy-first
    int qt, k0, kend, mode;                        // mode 0=direct,1=c0,2=c1
    if (rank < 16)        { qt = 16 + rank; k0 = 0;  kend = 15; mode = 1; }
    else {
        const int i = (rank - 16) >> 1;
        if ((rank & 1) == 0) { qt = 31 - i; k0 = 16; kend = qt; mode = 2; }
        else                 { qt = 15 - i; k0 = 0;  kend = qt; mode = 0; }
    }
    const int b = bh >> 4, h = bh & 15;
    const int sw = (quad ^ ((l15 >> 1) & 3)) * 8;
    const int ch = (lane & 3) ^ ((lane >> 3) & 3);
    unsigned short* pbase = sP + w * 1024;

    short8 ones;
#pragma unroll
    for (int jj = 0; jj < 8; ++jj) ones[jj] = (short)0x3F80;  // bf16 1.0

    const size_t qb = ((size_t)bh * SEQ + qt * 64 + w * 16 + l15) * 64 + quad * 8;
    const half8 qh0 = *(const half8*)(Qh + qb);
    const half8 qh1 = *(const half8*)(Qh + qb + 32);

    // lane l (<32) holds the mask word of k-tile l for this batch
    unsigned int mlo = 0xffffffffu, mhi = 0xffffffffu;
    if (lane < 32) {
        unsigned long long mw = mbits[b * 32 + lane];
        mlo = (unsigned int)mw;
        mhi = (unsigned int)(mw >> 32);
    }
    const bool fullmask =
        (__ballot((mlo & mhi) == 0xffffffffu) == ~0ull);

    const size_t kRow0 = ((size_t)bh * SEQ + w * 16 + (lane >> 2)) * 64 + ch * 8;
    const size_t vRow  = ((size_t)bh * 64 + w * 16 + (lane >> 2)) * SEQ + ch * 8;

    floatx4 O[4];
    floatx4 lAcc = (floatx4)0.f;
#pragma unroll
    for (int nf = 0; nf < 4; ++nf) O[nf] = (floatx4)0.f;

    const int mg = qt * 64 + w * 16 + l15;

    for (int kt = k0; kt <= kend; ++kt) {
        __syncthreads();
        {
            const size_t kg = kRow0 + (size_t)kt * 64 * 64;
            const size_t vg = vRow + (size_t)kt * 64;
            GLD_LDS16(Kh + kg,      sK + w * 512);
            GLD_LDS16(Kh + kg + 32, sK + 2048 + w * 512);
            GLD_LDS16(Vh + vg,      sV + w * 512);
            GLD_LDS16(Vh + vg + 32, sV + 2048 + w * 512);
        }
        __syncthreads();

        const bool diag = (kt == qt);
        unsigned int wlo = 0xffffffffu, whi = 0xffffffffu;
        if (!fullmask) {
            wlo = (unsigned int)__shfl((int)mlo, kt);
            whi = (unsigned int)__shfl((int)mhi, kt);
        }

        // ---- S^T = K Q^T (fp16), exp, pack bf16, stage P (wave-private) ----
#pragma unroll
        for (int nf = 0; nf < 4; ++nf) {
            const int base = (nf * 16 + l15) * 32 + sw;
            const half8 k0v = *(const half8*)&sK[base];
            const half8 k1v = *(const half8*)&sK[2048 + base];
            floatx4 s = (floatx4)0.f;
            s = HMFMA(k0v, qh0, s);
            s = HMFMA(k1v, qh1, s);

            float pv[4];
            if (fullmask && !diag) {               // wave-uniform fast path
#pragma unroll
                for (int r = 0; r < 4; ++r)
                    pv[r] = __expf(s[r] - 16.0f);
            } else {
                const int tb = kt * 64 + nf * 16 + quad * 4;
                const unsigned int msel = (nf & 2) ? whi : wlo;
                const int p4 = (nf & 1) * 16 + quad * 4;
#pragma unroll
                for (int r = 0; r < 4; ++r) {
                    bool ok = ((msel >> (p4 + r)) & 1u) != 0u;
                    if (diag) ok = ok && (tb + r <= mg);
                    pv[r] = ok ? __expf(s[r] - 16.0f) : 0.0f;
                }
            }
            uint32_t w0, w1;
            asm("v_cvt_pk_bf16_f32 %0, %1, %2" : "=v"(w0) : "v"(pv[0]), "v"(pv[1]));
            asm("v_cvt_pk_bf16_f32 %0, %1, %2" : "=v"(w1) : "v"(pv[2]), "v"(pv[3]));
            const int pos = (((nf & 1) * 2 + (quad >> 1)) ^ ((l15 >> 1) & 3));
            *(uint2*)(pbase + (nf >> 1) * 512 + l15 * 32 + pos * 8
                      + (quad & 1) * 4) = make_uint2(w0, w1);
        }

        const short8 pf0 = *(const short8*)(pbase + l15 * 32 + sw);
        const short8 pf1 = *(const short8*)(pbase + 512 + l15 * 32 + sw);

        // ---- l += P @ ones ; O += P @ V  (bf16) ----
        lAcc = BMFMA(pf0, ones, lAcc);
        lAcc = BMFMA(pf1, ones, lAcc);
#pragma unroll
        for (int nf = 0; nf < 4; ++nf) {
            const int vb = (nf * 16 + l15) * 32 + sw;
            floatx4 o = O[nf];
            o = BMFMA(pf0, *(const short8*)&sV[vb], o);
            o = BMFMA(pf1, *(const short8*)&sV[2048 + vb], o);
            O[nf] = o;
        }
    }

    if (mode == 0) {
        // ---- direct: divide by l, store fp16 ----
        float rl[4];
#pragma unroll
        for (int r = 0; r < 4; ++r) rl[r] = 1.0f / lAcc[r];
#pragma unroll
        for (int nf = 0; nf < 4; ++nf)
#pragma unroll
            for (int r = 0; r < 4; ++r) {
                const int tok = b * SEQ + qt * 64 + w * 16 + quad * 4 + r;
                const int col = h * 64 + nf * 16 + l15;
                attnx[(size_t)tok * 1024 + col] = f2h(O[nf][r] * rl[r]);
            }
    } else {
        // ---- partial: publish (O,l); second finisher merges inline ----
        const int qt16 = qt - 16;
        const size_t obase = (((size_t)bh * 16 + qt16) * 64) * 64;
        float* Op = Opart + ((mode == 2) ? 2097152 : 0) + obase;
#pragma unroll
        for (int nf = 0; nf < 4; ++nf)
#pragma unroll
            for (int r = 0; r < 4; ++r)
                Op[(w * 16 + quad * 4 + r) * 64 + nf * 16 + l15] = O[nf][r];
        if (l15 == 0) {
            float* lp = lpart + ((mode == 2) ? 32768 : 0)
                      + (bh * 16 + qt16) * 64;
#pragma unroll
            for (int r = 0; r < 4; ++r)
                lp[w * 16 + quad * 4 + r] = lAcc[r];
        }
        __threadfence();                           // publish before flag
        __syncthreads();
        if (tid == 0) sOld = atomicAdd(&flags[bh * 16 + qt16], 1);
        __syncthreads();
        if (sOld == 1) {                           // I'm second: merge
            const float* Oo = Opart + ((mode == 2) ? 0 : 2097152) + obase;
            const float* lo = lpart + ((mode == 2) ? 0 : 32768)
                            + (bh * 16 + qt16) * 64;
            float rl[4];
#pragma unroll
            for (int r = 0; r < 4; ++r)
                rl[r] = 1.0f / (lAcc[r] + lo[w * 16 + quad * 4 + r]);
#pragma unroll
            for (int nf = 0; nf < 4; ++nf)
#pragma unroll
                for (int r = 0; r < 4; ++r) {
                    const int tok = b * SEQ + qt * 64 + w * 16 + quad * 4 + r;
                    const int col = h * 64 + nf * 16 + l15;
                    float v = O[nf][r]
                            + Oo[(w * 16 + quad * 4 + r) * 64 + nf * 16 + l15];
                    attnx[(size_t)tok * 1024 + col] = f2h(v * rl[r]);
                }
        }
    }
}

// ---------------------------------------------------------------------------
extern "C" void kernel_launch(void* const* d_in, const int* in_sizes, int n_in,
                              void* d_out, int out_size, void* d_ws, size_t ws_size,
                              hipStream_t stream)
{
    const float* x    = (const float*)d_in[0];
    const int*   am   = (const int*)d_in[1];
    const float* Wqkv = (const float*)d_in[2];
    const float* bqkv = (const float*)d_in[3];
    const float* Wout = (const float*)d_in[4];
    const float* bout = (const float*)d_in[5];
    float* out = (float*)d_out;

    // ws layout (~105.2 MB):
    //   Bt fp16 6.29MB @0 | Bt2 fp16 2.10MB @6291456 | tab @8388608 |
    //   mbits @8912896 | attnx fp16 8.39MB @12582912 |
    //   Qh @62914560 | Kh @71303168 | Vh @79691776 (8.39MB each) |
    //   Axh fp16 8.39MB @88080384 (dead after gemm; reused as Opart c0) |
    //   Opart c1 8.39MB @96468992 | lpart 0.26MB @104857600 | flags 2KB
    char* ws = (char*)d_ws;
    unsigned short* Bt  = (unsigned short*)ws;
    unsigned short* Bt2 = (unsigned short*)(ws + 6291456);
    float2* tab = (float2*)(ws + 8388608);
    unsigned long long* mbits = (unsigned long long*)(ws + 8912896);
    unsigned short* attnx = (unsigned short*)(ws + 12582912);
    unsigned short* Qh = (unsigned short*)(ws + 62914560);
    unsigned short* Kh = (unsigned short*)(ws + 71303168);
    unsigned short* Vh = (unsigned short*)(ws + 79691776);
    unsigned short* Axh = (unsigned short*)(ws + 88080384);
    float* Opart = (float*)(ws + 88080384);              // c0 aliases dead Axh
    float* lpart = (float*)(ws + 104857600);
    int* flags = (int*)(ws + 104857600 + 262144);

    // 0) x -> Axh, W_qkv -> Bt, W_out -> Bt2, mask+flags, RoPE table
    split_inputs<<<6161, 256, 0, stream>>>(x, Wqkv, Wout, am,
                                           Axh, Bt, Bt2, mbits, tab, flags);

    // 1) FUSED: qkv GEMM + bias + RoPE + scale + Q/K/V stores (XCD slabs)
    gemm_qkv_fused<<<768, 256, 0, stream>>>(Axh, Bt, bqkv, tab, Qh, Kh, Vh);

    // 2) split-K MFMA flash attention with inline merge (1536 chunks)
    flash_mfma<<<1536, 256, 0, stream>>>(Qh, Kh, Vh, mbits, attnx,
                                         Opart, lpart, flags);

    // 3) out = attn @ W_out + b  (XCD slabs: 8 x (4M x 8N))
    gemm_mfma_h<2, 2, 4, 4><<<256, 256, 0, stream>>>(
        attnx, 1024, Bt2, 1024, bout, out, 1024, 4, 8);
}

// Round 9
// 183.993 us; speedup vs baseline: 1.6638x; 1.6638x over previous
//
#include <hip/hip_runtime.h>
#include <math.h>
#include <stdint.h>

#define D_MODEL 1024
#define N_HEADS 16
#define HEAD_DIM 64
#define BATCH 2
#define SEQ 2048
#define TOKENS (BATCH * SEQ)   // 4096

typedef __attribute__((ext_vector_type(8))) short short8;      // 8 bf16
typedef __attribute__((ext_vector_type(8))) _Float16 half8;    // 8 fp16
typedef __attribute__((ext_vector_type(4))) float floatx4;     // MFMA C/D frag

#define BMFMA(a, b, c) __builtin_amdgcn_mfma_f32_16x16x32_bf16(a, b, c, 0, 0, 0)
#define HMFMA(a, b, c) __builtin_amdgcn_mfma_f32_16x16x32_f16(a, b, c, 0, 0, 0)

__device__ __forceinline__ unsigned short f2bf(float f) {
    uint32_t u = __float_as_uint(f);
    u += 0x7fffu + ((u >> 16) & 1u);
    return (unsigned short)(u >> 16);
}
__device__ __forceinline__ float bf2f(unsigned short h) {
    return __uint_as_float(((uint32_t)h) << 16);
}
__device__ __forceinline__ unsigned short f2h(float f) {
    union { _Float16 h; unsigned short u; } cv;
    cv.h = (_Float16)f;            // RNE
    return cv.u;
}
__device__ __forceinline__ float h2f(unsigned short u) {
    union { unsigned short u; _Float16 h; } cv;
    cv.u = u;
    return (float)cv.h;
}

// async global -> LDS, 16B per lane; LDS dest = wave-uniform base + lane*16
#define GLD_LDS16(gp, lp) __builtin_amdgcn_global_load_lds(                 \
    (const __attribute__((address_space(1))) void*)(gp),                    \
    (__attribute__((address_space(3))) void*)(lp), 16, 0, 0)

// ---------------------------------------------------------------------------
// Merged input prep:
//   blocks [0,2048)      : x -> Axh (single fp16 [4096][1024])
//   blocks [2048,5120)   : W_qkv -> Bt (transpose, single fp16 [3072n][1024k])
//   blocks [5120,6144)   : W_out -> Bt2 (transpose, single fp16 [1024n][1024k])
//   block  6144          : attention_mask -> 64-bit per-k-tile bitmask
//   blocks [6145,6161)   : RoPE cos/sin table [t][32] float2
// ---------------------------------------------------------------------------
__global__ __launch_bounds__(256) void split_inputs(
    const float* __restrict__ X, const float* __restrict__ Wqkv,
    const float* __restrict__ Wout, const int* __restrict__ am,
    unsigned short* __restrict__ Axh, unsigned short* __restrict__ Bt,
    unsigned short* __restrict__ Bt2, unsigned long long* __restrict__ mbits,
    float2* __restrict__ tab)
{
    __shared__ float t[32][33];
    const int tid = threadIdx.x;
    const int bid = blockIdx.x;
    if (bid < 2048) {
        const int idx = bid * 2048 + tid * 8;
        const int row = idx >> 10;
        const int c = idx & 1023;
        float4 v0 = *(const float4*)(X + (size_t)row * 1024 + c);
        float4 v1 = *(const float4*)(X + (size_t)row * 1024 + c + 4);
        float f[8] = {v0.x, v0.y, v0.z, v0.w, v1.x, v1.y, v1.z, v1.w};
        uint32_t p[4];
#pragma unroll
        for (int j = 0; j < 4; ++j)
            p[j] = (uint32_t)f2h(f[2 * j]) | ((uint32_t)f2h(f[2 * j + 1]) << 16);
        *(uint4*)(Axh + (size_t)row * 1024 + c) = *(uint4*)p;
    } else if (bid < 5120) {
        const int id = bid - 2048;                 // 0..3071
        const int n0 = (id % 96) * 32, k0 = (id / 96) * 32;
        const int c = tid & 31, r = tid >> 5;
#pragma unroll
        for (int i = 0; i < 4; ++i)
            t[r + 8 * i][c] = Wqkv[(size_t)(k0 + r + 8 * i) * 3072 + n0 + c];
        __syncthreads();
#pragma unroll
        for (int i = 0; i < 4; ++i) {
            int dn = r + 8 * i;
            Bt[(size_t)(n0 + dn) * 1024 + k0 + c] = f2h(t[c][dn]);
        }
    } else if (bid < 6144) {
        const int id = bid - 5120;                 // 0..1023: W_out 32x32 tiles
        const int n0 = (id & 31) * 32, k0 = (id >> 5) * 32;
        const int c = tid & 31, r = tid >> 5;
#pragma unroll
        for (int i = 0; i < 4; ++i)
            t[r + 8 * i][c] = Wout[(size_t)(k0 + r + 8 * i) * 1024 + n0 + c];
        __syncthreads();
#pragma unroll
        for (int i = 0; i < 4; ++i) {
            int dn = r + 8 * i;
            Bt2[(size_t)(n0 + dn) * 1024 + k0 + c] = f2h(t[c][dn]);
        }
    } else if (bid == 6144) {
        // mask bitmap: one uint64 per 64-token tile (B*SEQ/64 = 64 tiles)
        if (tid < 64) {
            const int* a = am + tid * 64;
            unsigned long long m = 0ull;
            for (int j = 0; j < 64; ++j)
                m |= (unsigned long long)(a[j] != 0 ? 1u : 0u) << j;
            mbits[tid] = m;
        }
    } else {
        // RoPE table: 2048 x 32 float2 (cos, sin)
        const int i = bid - 6145;                  // 0..15
#pragma unroll
        for (int e = 0; e < 16; ++e) {
            int idx = i * 4096 + e * 256 + tid;
            int tt = idx >> 5, pr = idx & 31;
            double ex = (double)(2 * pr) / 64.0;
            float inv = (float)exp2(-ex * 13.287712379549449);
            float ang = (float)tt * inv;
            float s, c;
            __sincosf(ang, &s, &c);
            tab[idx] = make_float2(c, s);
        }
    }
}

// ---------------------------------------------------------------------------
// FUSED QKV projection + RoPE + Q-scale + layout split, XCD-slab grid:
// 768 blocks = 8 slabs (blockIdx%8 -> XCD) of 8M x 12N tiles.
// ---------------------------------------------------------------------------
__global__ __launch_bounds__(256) void gemm_qkv_fused(
    const unsigned short* __restrict__ Axh, const unsigned short* __restrict__ Bt,
    const float* __restrict__ bias, const float2* __restrict__ tab,
    unsigned short* __restrict__ Qh, unsigned short* __restrict__ Kh,
    unsigned short* __restrict__ Vh)
{
    __shared__ __align__(16) unsigned short sA0[4096], sA1[4096];
    __shared__ __align__(16) unsigned short sB0[4096], sB1[4096];

    const int tid = threadIdx.x;
    const int w = tid >> 6, lane = tid & 63;
    const int l15 = lane & 15, quad = lane >> 4;
    const int wm = w >> 1, wn = w & 1;

    const int lin = blockIdx.x;
    const int s = lin & 7;                 // XCD (HW round-robin on bid%8)
    const int loc = lin >> 3;              // 0..95 within slab
    const int m0 = ((s >> 1) * 8 + loc / 12) * 128;   // 4 slabs along M
    const int n0 = ((s & 1) * 12 + loc % 12) * 128;   // 2 slabs along N

    const int ch = (lane & 3) ^ ((lane >> 3) & 3);
    const int sw = (quad ^ ((l15 >> 1) & 3)) * 8;

    const unsigned short* aG[2];
    const unsigned short* bG[2];
#pragma unroll
    for (int i = 0; i < 2; ++i) {
        aG[i] = Axh + (size_t)(m0 + (w * 2 + i) * 16 + (lane >> 2)) * 1024 + ch * 8;
        bG[i] = Bt + (size_t)(n0 + (w * 2 + i) * 16 + (lane >> 2)) * 1024 + ch * 8;
    }

    floatx4 acc[4][4];
#pragma unroll
    for (int fm = 0; fm < 4; ++fm)
#pragma unroll
        for (int fn = 0; fn < 4; ++fn) acc[fm][fn] = (floatx4)0.f;

    for (int ks = 0; ks < 16; ++ks) {
        const int ko = ks * 64;
        __syncthreads();
#pragma unroll
        for (int i = 0; i < 2; ++i) {
            GLD_LDS16(aG[i] + ko,      sA0 + (w * 2 + i) * 512);
            GLD_LDS16(aG[i] + ko + 32, sA1 + (w * 2 + i) * 512);
            GLD_LDS16(bG[i] + ko,      sB0 + (w * 2 + i) * 512);
            GLD_LDS16(bG[i] + ko + 32, sB1 + (w * 2 + i) * 512);
        }
        __syncthreads();

        half8 a0[4], a1[4], b0[4], b1[4];
#pragma unroll
        for (int fm = 0; fm < 4; ++fm) {
            const int off = ((wm * 4 + fm) * 16 + l15) * 32 + sw;
            a0[fm] = *(const half8*)&sA0[off];
            a1[fm] = *(const half8*)&sA1[off];
        }
#pragma unroll
        for (int fn = 0; fn < 4; ++fn) {
            const int off = ((wn * 4 + fn) * 16 + l15) * 32 + sw;
            b0[fn] = *(const half8*)&sB0[off];
            b1[fn] = *(const half8*)&sB1[off];
        }
#pragma unroll
        for (int fm = 0; fm < 4; ++fm)
#pragma unroll
            for (int fn = 0; fn < 4; ++fn) {
                floatx4 a = acc[fm][fn];
                a = HMFMA(a0[fm], b0[fn], a);
                a = HMFMA(a1[fm], b1[fn], a);
                acc[fm][fn] = a;
            }
    }

    // ---- fused epilogue ----
    if (n0 < 2048) {
        // Q or K: bias + RoPE (partner in lane^1) + (Q: 1/8 scale)
        const bool isQ = (n0 < 1024);
        unsigned short* dst = isQ ? Qh : Kh;
        const float qs = isQ ? 0.125f : 1.0f;
#pragma unroll
        for (int fm = 0; fm < 4; ++fm)
#pragma unroll
            for (int fn = 0; fn < 4; ++fn) {
                const int col = n0 + (wn * 4 + fn) * 16 + l15;
                const int hcol = col & 1023;
                const int hh = hcol >> 6, d = hcol & 63;
                const int pr = d >> 1;
                const bool odd = (d & 1) != 0;
                const float bv = bias[col];
#pragma unroll
                for (int r = 0; r < 4; ++r) {
                    const int row = m0 + (wm * 4 + fm) * 16 + quad * 4 + r;
                    const int tg = row & 2047, bb = row >> 11;
                    float val = acc[fm][fn][r] + bv;
                    float part = __shfl_xor(val, 1);
                    const float2 cs = tab[tg * 32 + pr];
                    float res = odd ? (part * cs.y + val * cs.x)
                                    : (val * cs.x - part * cs.y);
                    dst[((size_t)(bb * 16 + hh) * SEQ + tg) * 64 + d] =
                        f2h(res * qs);
                }
            }
    } else {
        // V: bias, bf16, transposed [bh][d][2048]; 4 consecutive t per store
#pragma unroll
        for (int fm = 0; fm < 4; ++fm)
#pragma unroll
            for (int fn = 0; fn < 4; ++fn) {
                const int col = n0 + (wn * 4 + fn) * 16 + l15;
                const int hcol = col & 1023;
                const int hh = hcol >> 6, d = hcol & 63;
                const float bv = bias[col];
                const int row0 = m0 + (wm * 4 + fm) * 16 + quad * 4;
                const int tg0 = row0 & 2047, bb = row0 >> 11;
                uint32_t pk0 = (uint32_t)f2bf(acc[fm][fn][0] + bv)
                             | ((uint32_t)f2bf(acc[fm][fn][1] + bv) << 16);
                uint32_t pk1 = (uint32_t)f2bf(acc[fm][fn][2] + bv)
                             | ((uint32_t)f2bf(acc[fm][fn][3] + bv) << 16);
                *(uint2*)(Vh + ((size_t)(bb * 16 + hh) * 64 + d) * SEQ + tg0) =
                    make_uint2(pk0, pk1);
            }
    }
}

// ---------------------------------------------------------------------------
// Single-precision fp16 MFMA GEMM (out-projection), fp32 output, XCD slabs.
// ---------------------------------------------------------------------------
template<int WM, int WN, int FM, int FN>
__global__ __launch_bounds__(256) void gemm_mfma_h(
    const unsigned short* __restrict__ A, int lda,
    const unsigned short* __restrict__ Bt, int ldb,
    const float* __restrict__ bias, float* __restrict__ C, int ldc,
    int mPerSlab, int nTilesN)
{
    constexpr int BM = WM * FM * 16;
    constexpr int BN = WN * FN * 16;
    constexpr int NA = BM / 64;
    constexpr int NB = BN / 64;

    __shared__ __align__(16) unsigned short sA0[BM * 32];
    __shared__ __align__(16) unsigned short sA1[BM * 32];
    __shared__ __align__(16) unsigned short sB0[BN * 32];
    __shared__ __align__(16) unsigned short sB1[BN * 32];

    const int tid = threadIdx.x;
    const int w = tid >> 6, lane = tid & 63;
    const int l15 = lane & 15, quad = lane >> 4;
    const int wm = w / WN, wn = w % WN;

    const int lin = blockIdx.x;
    const int s = lin & 7, loc = lin >> 3;
    const int m0 = (s * mPerSlab + loc / nTilesN) * BM;
    const int n0 = (loc % nTilesN) * BN;

    const int ch = (lane & 3) ^ ((lane >> 3) & 3);
    const int sw = (quad ^ ((l15 >> 1) & 3)) * 8;

    const unsigned short* aG[NA];
    const unsigned short* bG[NB];
#pragma unroll
    for (int i = 0; i < NA; ++i)
        aG[i] = A + (size_t)(m0 + (w * NA + i) * 16 + (lane >> 2)) * lda + ch * 8;
#pragma unroll
    for (int i = 0; i < NB; ++i)
        bG[i] = Bt + (size_t)(n0 + (w * NB + i) * 16 + (lane >> 2)) * ldb + ch * 8;

    floatx4 acc[FM][FN];
#pragma unroll
    for (int fm = 0; fm < FM; ++fm)
#pragma unroll
        for (int fn = 0; fn < FN; ++fn) acc[fm][fn] = (floatx4)0.f;

    for (int ks = 0; ks < 16; ++ks) {
        const int ko = ks * 64;
        __syncthreads();
#pragma unroll
        for (int i = 0; i < NA; ++i) {
            GLD_LDS16(aG[i] + ko,      sA0 + (w * NA + i) * 512);
            GLD_LDS16(aG[i] + ko + 32, sA1 + (w * NA + i) * 512);
        }
#pragma unroll
        for (int i = 0; i < NB; ++i) {
            GLD_LDS16(bG[i] + ko,      sB0 + (w * NB + i) * 512);
            GLD_LDS16(bG[i] + ko + 32, sB1 + (w * NB + i) * 512);
        }
        __syncthreads();

        half8 a0[FM], a1[FM], b0[FN], b1[FN];
#pragma unroll
        for (int fm = 0; fm < FM; ++fm) {
            const int off = ((wm * FM + fm) * 16 + l15) * 32 + sw;
            a0[fm] = *(const half8*)&sA0[off];
            a1[fm] = *(const half8*)&sA1[off];
        }
#pragma unroll
        for (int fn = 0; fn < FN; ++fn) {
            const int off = ((wn * FN + fn) * 16 + l15) * 32 + sw;
            b0[fn] = *(const half8*)&sB0[off];
            b1[fn] = *(const half8*)&sB1[off];
        }
#pragma unroll
        for (int fm = 0; fm < FM; ++fm)
#pragma unroll
            for (int fn = 0; fn < FN; ++fn) {
                floatx4 a = acc[fm][fn];
                a = HMFMA(a0[fm], b0[fn], a);
                a = HMFMA(a1[fm], b1[fn], a);
                acc[fm][fn] = a;
            }
    }

#pragma unroll
    for (int fm = 0; fm < FM; ++fm)
#pragma unroll
        for (int fn = 0; fn < FN; ++fn) {
            int col = n0 + (wn * FN + fn) * 16 + l15;
            float bv = bias[col];
#pragma unroll
            for (int r = 0; r < 4; ++r) {
                int row = m0 + (wm * FM + fm) * 16 + quad * 4 + r;
                C[(size_t)row * ldc + col] = acc[fm][fn][r] + bv;
            }
        }
}

// ---------------------------------------------------------------------------
// MFMA flash attention, R19 = R17 split-K (NO inline merge — device-scope
// fence+atomic per block measured 168 µs in R18; the launch boundary is the
// cheap device-wide fence). Partials merged by flash_merge.
// ---------------------------------------------------------------------------
__global__ __launch_bounds__(256, 6) void flash_mfma(
    const unsigned short* __restrict__ Qh, const unsigned short* __restrict__ Kh,
    const unsigned short* __restrict__ Vh,
    const unsigned long long* __restrict__ mbits,
    unsigned short* __restrict__ attnx,
    float* __restrict__ Opart, float* __restrict__ lpart)
{
    __shared__ __align__(16) unsigned short sK[4096];
    __shared__ __align__(16) unsigned short sV[4096];
    __shared__ __align__(16) unsigned short sP[4096];

    const int tid = threadIdx.x;
    const int lane = tid & 63, w = tid >> 6;
    const int l15 = lane & 15, quad = lane >> 4;
    const int lin0 = blockIdx.x;
    const int xcd = lin0 & 7, idx = lin0 >> 3;     // 1536 = 8 XCD * 192
    const int bh = xcd * 4 + (idx & 3);            // 4 bh per XCD (L2-resident)
    const int rank = idx >> 2;                     // 0..47, heavy-first
    int qt, k0, kend, mode;                        // mode 0=direct,1=c0,2=c1
    if (rank < 16)        { qt = 16 + rank; k0 = 0;  kend = 15; mode = 1; }
    else {
        const int i = (rank - 16) >> 1;
        if ((rank & 1) == 0) { qt = 31 - i; k0 = 16; kend = qt; mode = 2; }
        else                 { qt = 15 - i; k0 = 0;  kend = qt; mode = 0; }
    }
    const int b = bh >> 4, h = bh & 15;
    const int sw = (quad ^ ((l15 >> 1) & 3)) * 8;
    const int ch = (lane & 3) ^ ((lane >> 3) & 3);
    unsigned short* pbase = sP + w * 1024;

    short8 ones;
#pragma unroll
    for (int jj = 0; jj < 8; ++jj) ones[jj] = (short)0x3F80;  // bf16 1.0

    const size_t qb = ((size_t)bh * SEQ + qt * 64 + w * 16 + l15) * 64 + quad * 8;
    const half8 qh0 = *(const half8*)(Qh + qb);
    const half8 qh1 = *(const half8*)(Qh + qb + 32);

    // lane l (<32) holds the mask word of k-tile l for this batch
    unsigned int mlo = 0xffffffffu, mhi = 0xffffffffu;
    if (lane < 32) {
        unsigned long long mw = mbits[b * 32 + lane];
        mlo = (unsigned int)mw;
        mhi = (unsigned int)(mw >> 32);
    }
    const bool fullmask =
        (__ballot((mlo & mhi) == 0xffffffffu) == ~0ull);

    const size_t kRow0 = ((size_t)bh * SEQ + w * 16 + (lane >> 2)) * 64 + ch * 8;
    const size_t vRow  = ((size_t)bh * 64 + w * 16 + (lane >> 2)) * SEQ + ch * 8;

    floatx4 O[4];
    floatx4 lAcc = (floatx4)0.f;
#pragma unroll
    for (int nf = 0; nf < 4; ++nf) O[nf] = (floatx4)0.f;

    const int mg = qt * 64 + w * 16 + l15;

    for (int kt = k0; kt <= kend; ++kt) {
        __syncthreads();
        {
            const size_t kg = kRow0 + (size_t)kt * 64 * 64;
            const size_t vg = vRow + (size_t)kt * 64;
            GLD_LDS16(Kh + kg,      sK + w * 512);
            GLD_LDS16(Kh + kg + 32, sK + 2048 + w * 512);
            GLD_LDS16(Vh + vg,      sV + w * 512);
            GLD_LDS16(Vh + vg + 32, sV + 2048 + w * 512);
        }
        __syncthreads();

        const bool diag = (kt == qt);
        unsigned int wlo = 0xffffffffu, whi = 0xffffffffu;
        if (!fullmask) {
            wlo = (unsigned int)__shfl((int)mlo, kt);
            whi = (unsigned int)__shfl((int)mhi, kt);
        }

        // ---- S^T = K Q^T (fp16), exp, pack bf16, stage P (wave-private) ----
#pragma unroll
        for (int nf = 0; nf < 4; ++nf) {
            const int base = (nf * 16 + l15) * 32 + sw;
            const half8 k0v = *(const half8*)&sK[base];
            const half8 k1v = *(const half8*)&sK[2048 + base];
            floatx4 s = (floatx4)0.f;
            s = HMFMA(k0v, qh0, s);
            s = HMFMA(k1v, qh1, s);

            float pv[4];
            if (fullmask && !diag) {               // wave-uniform fast path
#pragma unroll
                for (int r = 0; r < 4; ++r)
                    pv[r] = __expf(s[r] - 16.0f);
            } else {
                const int tb = kt * 64 + nf * 16 + quad * 4;
                const unsigned int msel = (nf & 2) ? whi : wlo;
                const int p4 = (nf & 1) * 16 + quad * 4;
#pragma unroll
                for (int r = 0; r < 4; ++r) {
                    bool ok = ((msel >> (p4 + r)) & 1u) != 0u;
                    if (diag) ok = ok && (tb + r <= mg);
                    pv[r] = ok ? __expf(s[r] - 16.0f) : 0.0f;
                }
            }
            uint32_t w0, w1;
            asm("v_cvt_pk_bf16_f32 %0, %1, %2" : "=v"(w0) : "v"(pv[0]), "v"(pv[1]));
            asm("v_cvt_pk_bf16_f32 %0, %1, %2" : "=v"(w1) : "v"(pv[2]), "v"(pv[3]));
            const int pos = (((nf & 1) * 2 + (quad >> 1)) ^ ((l15 >> 1) & 3));
            *(uint2*)(pbase + (nf >> 1) * 512 + l15 * 32 + pos * 8
                      + (quad & 1) * 4) = make_uint2(w0, w1);
        }

        const short8 pf0 = *(const short8*)(pbase + l15 * 32 + sw);
        const short8 pf1 = *(const short8*)(pbase + 512 + l15 * 32 + sw);

        // ---- l += P @ ones ; O += P @ V  (bf16) ----
        lAcc = BMFMA(pf0, ones, lAcc);
        lAcc = BMFMA(pf1, ones, lAcc);
#pragma unroll
        for (int nf = 0; nf < 4; ++nf) {
            const int vb = (nf * 16 + l15) * 32 + sw;
            floatx4 o = O[nf];
            o = BMFMA(pf0, *(const short8*)&sV[vb], o);
            o = BMFMA(pf1, *(const short8*)&sV[2048 + vb], o);
            O[nf] = o;
        }
    }

    if (mode == 0) {
        // ---- direct: divide by l, store fp16 ----
        float rl[4];
#pragma unroll
        for (int r = 0; r < 4; ++r) rl[r] = 1.0f / lAcc[r];
#pragma unroll
        for (int nf = 0; nf < 4; ++nf)
#pragma unroll
            for (int r = 0; r < 4; ++r) {
                const int tok = b * SEQ + qt * 64 + w * 16 + quad * 4 + r;
                const int col = h * 64 + nf * 16 + l15;
                attnx[(size_t)tok * 1024 + col] = f2h(O[nf][r] * rl[r]);
            }
    } else {
        // ---- partial: store O (f32) and l (f32); merged by flash_merge ----
        const int qt16 = qt - 16;
        float* Op = Opart + ((mode == 2) ? 2097152 : 0)
                  + (((size_t)bh * 16 + qt16) * 64) * 64;
#pragma unroll
        for (int nf = 0; nf < 4; ++nf)
#pragma unroll
            for (int r = 0; r < 4; ++r)
                Op[(w * 16 + quad * 4 + r) * 64 + nf * 16 + l15] = O[nf][r];
        if (l15 == 0) {
            float* lp = lpart + ((mode == 2) ? 32768 : 0)
                      + (bh * 16 + qt16) * 64;
#pragma unroll
            for (int r = 0; r < 4; ++r)
                lp[w * 16 + quad * 4 + r] = lAcc[r];
        }
    }
}

// ---------------------------------------------------------------------------
// Merge split-K partials: out = (O0+O1)/(l0+l1), store fp16.
// 512 blocks = 32 bh x 16 q-tiles (qt 16..31).
// ---------------------------------------------------------------------------
__global__ __launch_bounds__(256) void flash_merge(
    const float* __restrict__ Opart, const float* __restrict__ lpart,
    unsigned short* __restrict__ attnx)
{
    const int bh = blockIdx.x >> 4, qt16 = blockIdx.x & 15;
    const int b = bh >> 4, h = bh & 15;
    const int tid = threadIdx.x;
    const int q = tid >> 2, dblk = (tid & 3) * 16;
    const size_t ob = (((size_t)bh * 16 + qt16) * 64 + q) * 64 + dblk;
    const int lb = (bh * 16 + qt16) * 64 + q;
    const float rl = 1.0f / (lpart[lb] + lpart[lb + 32768]);

    uint32_t ph[8];
#pragma unroll
    for (int i = 0; i < 4; ++i) {
        float4 a = *(const float4*)(Opart + ob + 4 * i);
        float4 c = *(const float4*)(Opart + ob + 2097152 + 4 * i);
        float f0 = (a.x + c.x) * rl, f1 = (a.y + c.y) * rl;
        float f2 = (a.z + c.z) * rl, f3 = (a.w + c.w) * rl;
        ph[2 * i]     = (uint32_t)f2h(f0) | ((uint32_t)f2h(f1) << 16);
        ph[2 * i + 1] = (uint32_t)f2h(f2) | ((uint32_t)f2h(f3) << 16);
    }
    const int tok = b * SEQ + (16 + qt16) * 64 + q;
    unsigned short* dst = attnx + (size_t)tok * 1024 + h * 64 + dblk;
    *(uint4*)dst = *(uint4*)&ph[0];
    *(uint4*)(dst + 8) = *(uint4*)&ph[4];
}

// ---------------------------------------------------------------------------
extern "C" void kernel_launch(void* const* d_in, const int* in_sizes, int n_in,
                              void* d_out, int out_size, void* d_ws, size_t ws_size,
                              hipStream_t stream)
{
    const float* x    = (const float*)d_in[0];
    const int*   am   = (const int*)d_in[1];
    const float* Wqkv = (const float*)d_in[2];
    const float* bqkv = (const float*)d_in[3];
    const float* Wout = (const float*)d_in[4];
    const float* bout = (const float*)d_in[5];
    float* out = (float*)d_out;

    // ws layout (~105 MB):
    //   Bt fp16 6.29MB @0 | Bt2 fp16 2.10MB @6291456 | tab @8388608 |
    //   mbits @8912896 | attnx fp16 8.39MB @12582912 |
    //   Qh @62914560 | Kh @71303168 | Vh @79691776 (8.39MB each) |
    //   Axh fp16 8.39MB @88080384 (dead after gemm; reused as Opart c0) |
    //   Opart c1 8.39MB @96468992 | lpart 0.26MB @104857600
    char* ws = (char*)d_ws;
    unsigned short* Bt  = (unsigned short*)ws;
    unsigned short* Bt2 = (unsigned short*)(ws + 6291456);
    float2* tab = (float2*)(ws + 8388608);
    unsigned long long* mbits = (unsigned long long*)(ws + 8912896);
    unsigned short* attnx = (unsigned short*)(ws + 12582912);
    unsigned short* Qh = (unsigned short*)(ws + 62914560);
    unsigned short* Kh = (unsigned short*)(ws + 71303168);
    unsigned short* Vh = (unsigned short*)(ws + 79691776);
    unsigned short* Axh = (unsigned short*)(ws + 88080384);
    float* Opart = (float*)(ws + 88080384);              // c0 aliases dead Axh
    float* lpart = (float*)(ws + 104857600);

    // 0) x -> Axh, W_qkv -> Bt, W_out -> Bt2, mask -> mbits, RoPE table
    split_inputs<<<6161, 256, 0, stream>>>(x, Wqkv, Wout, am,
                                           Axh, Bt, Bt2, mbits, tab);

    // 1) FUSED: qkv GEMM + bias + RoPE + scale + Q/K/V stores (XCD slabs)
    gemm_qkv_fused<<<768, 256, 0, stream>>>(Axh, Bt, bqkv, tab, Qh, Kh, Vh);

    // 2) split-K MFMA flash attention (1536 chunks) + separate merge
    flash_mfma<<<1536, 256, 0, stream>>>(Qh, Kh, Vh, mbits, attnx,
                                         Opart, lpart);
    flash_merge<<<512, 256, 0, stream>>>(Opart, lpart, attnx);

    // 3) out = attn @ W_out + b  (XCD slabs: 8 x (4M x 8N))
    gemm_mfma_h<2, 2, 4, 4><<<256, 256, 0, stream>>>(
        attnx, 1024, Bt2, 1024, bout, out, 1024, 4, 8);
}